// Round 21
// baseline (215.330 us; speedup 1.0000x reference)
//
#include <hip/hip_runtime.h>

// SplineCNN on MI355X — aggregate-before-GEMM, L2-direct gather (R16 base).
//
// Math order: s[n, k*CIN+c] = deginv * sum_{m in N(n)} basis_k(n,m) * h[m,c],
// root column appended -> one dense GEMM per layer:
//   out = relu( [s | h] @ [w; root] + bias ),  K = 10*CIN, N = 64.
// Measured best 206.3us (R20). Design ledger:
//  - gather: lean body, VGPR<=64 via launch_bounds(256,8) -> 8 waves/SIMD
//    (R13); precomputed tap weights in edge_w (R14). Deeper pipelines/unrolls
//    spill or halve occupancy (R8/R11/R18); slot-parallel (R12), fusion
//    (R7/R17), quadrant-per-wave (R10) all falsified.
//  - preprocess: barrier-free wave-per-row, two ballot passes, no LDS (R16);
//    merged with x->fp16 convert + weight pack + gmax zero.
//  - GEMM: M-tile 64->32 (R20, -7.4us: 2 blocks/CU interleave load stalls).
//    THIS ROUND: M-tile 32->16 (grid 1024 = 4 blocks/CU, LDS 23KB). Wave owns
//    one 16x16 output tile (1 MFMA/K-chunk); 4-way inter-block overlap of the
//    K-loop's barrier + HBM A-load latency. Same K-order -> bit-identical.
//  - XCD swizzle on gather: batch b's blocks on XCD b>>2 (h L2-resident).
// All tensors fp16 (fp32 accumulate in gather + MFMA); layer-2 GEMM epilogue
// fuses global max-pool via uint-bitcast atomicMax (relu >= 0).

#define B_   32
#define N_   512
#define F_   64
#define CAP  128          // max neighbors per node (mean ~31; P(>128) ~ 18 sigma)

typedef float f32x4 __attribute__((ext_vector_type(4)));
typedef _Float16 f16x8 __attribute__((ext_vector_type(8)));
typedef _Float16 f16x2 __attribute__((ext_vector_type(2)));

// ---------------- preprocess: wave-per-row, barrier-free ----------------
// edge_m[row*CAP+i] = neighbor index m; edge_w[row*CAP+i] = {w00,w01,w10,w11}
// (bilinear tap weights, f32, precomputed). Sorted by quad = kx0 + 2*ky0,
// ascending m within each quad. cnt4[row] = clamped cumulative quad counts;
// deginv = 1/clip(deg,1). Grid 2048 x 512: wave w of block i handles row
// i*8+w. Also merged prep (x fp32->fp16 + pack [w;root] -> Wt) + gmax zero.
__global__ __launch_bounds__(512, 8) void preprocess_kernel(
    const float* __restrict__ adj, const float* __restrict__ coord,
    int* __restrict__ edge_m, float4* __restrict__ edge_w,
    int4* __restrict__ cnt4,
    float* __restrict__ deginv, unsigned int* __restrict__ gmax,
    const float* __restrict__ x, _Float16* __restrict__ hx,
    const float* __restrict__ w0, const float* __restrict__ root0,
    const float* __restrict__ w1, const float* __restrict__ root1,
    const float* __restrict__ w2, const float* __restrict__ root2,
    _Float16* __restrict__ wt0, _Float16* __restrict__ wt1,
    _Float16* __restrict__ wt2) {
  int tid = threadIdx.x, wave = tid >> 6, lane = tid & 63;
  if (tid == 0) gmax[blockIdx.x] = 0u;   // grid 2048 == B_*F_

  // ---- merged prep: idx space [0, R*32) convx; then packw for 3 layers ----
  {
    int idx = blockIdx.x * 512 + tid;    // covers 1,048,576 >= 688,128
    const int CX = B_ * N_ * 32;
    const int S0 = 64 * 1280, S1 = 64 * 640;
    if (idx < CX) {
      float4 v = ((const float4*)x)[idx];
      f16x2 p0, p1;
      p0[0] = (_Float16)v.x; p0[1] = (_Float16)v.y;
      p1[0] = (_Float16)v.z; p1[1] = (_Float16)v.w;
      uint2 u;
      u.x = __builtin_bit_cast(unsigned, p0);
      u.y = __builtin_bit_cast(unsigned, p1);
      ((uint2*)hx)[idx] = u;
    } else if (idx < CX + S0 + 2 * S1) {
      int r = idx - CX;
      const float *w, *root; _Float16* wt; int KP, CIN;
      if (r < S0)           { w = w0; root = root0; wt = wt0; KP = 1280; CIN = 128; }
      else if (r < S0 + S1) { w = w1; root = root1; wt = wt1; KP = 640;  CIN = 64;  r -= S0; }
      else                  { w = w2; root = root2; wt = wt2; KP = 640;  CIN = 64;  r -= S0 + S1; }
      int f = r / KP, k = r - f * KP;
      int ks = k / CIN, c = k - ks * CIN;
      float v = (ks < 9) ? w[((size_t)ks * CIN + c) * F_ + f]
                         : root[(size_t)c * F_ + f];
      wt[(size_t)f * KP + k] = (_Float16)v;
    }
  }

  int row = blockIdx.x * 8 + wave;       // one row per wave
  int b = row >> 9;
  float cxn = coord[(size_t)row * 2 + 0];
  float cyn = coord[(size_t)row * 2 + 1];

  // ---- pass 1: load + classify 8 chunks of 64; wave-uniform quad totals ----
  int   pq[8];                  // quad (0..3) or -1 if no edge
  float pfx[8], pfy[8];
  int q0 = 0, q1 = 0, q2 = 0, q3 = 0;
  #pragma unroll
  for (int c = 0; c < 8; ++c) {
    int m = c * 64 + lane;
    float a = adj[(size_t)row * N_ + m];
    bool flag = (a != 0.0f);
    float cxm = coord[(size_t)(b * N_ + m) * 2 + 0];
    float cym = coord[(size_t)(b * N_ + m) * 2 + 1];
    float vx = cxm - cxn + 1.0f;         // = u*2 (K-1 = 2, u in [0,1])
    float vy = cym - cyn + 1.0f;
    float i0x = fminf(fmaxf(floorf(vx), 0.0f), 1.0f);
    float i0y = fminf(fmaxf(floorf(vy), 0.0f), 1.0f);
    pfx[c] = vx - i0x;
    pfy[c] = vy - i0y;
    int quad = (int)i0x + 2 * (int)i0y;  // 0..3
    pq[c] = flag ? quad : -1;
    q0 += __popcll(__ballot(flag && quad == 0));
    q1 += __popcll(__ballot(flag && quad == 1));
    q2 += __popcll(__ballot(flag && quad == 2));
    q3 += __popcll(__ballot(flag && quad == 3));
  }
  int qt0 = q0, qt1 = q0 + q1, qt2 = qt1 + q2, qt3 = qt2 + q3;

  // ---- pass 2: running per-quad offsets -> quad-sorted edge writes ----
  int ro0 = 0, ro1 = qt0, ro2 = qt1, ro3 = qt2;   // quad base offsets
  #pragma unroll
  for (int c = 0; c < 8; ++c) {
    unsigned long long b0 = __ballot(pq[c] == 0);
    unsigned long long b1 = __ballot(pq[c] == 1);
    unsigned long long b2 = __ballot(pq[c] == 2);
    unsigned long long b3 = __ballot(pq[c] == 3);
    int q = pq[c];
    if (q >= 0) {
      unsigned long long myb = (q == 0) ? b0 : (q == 1) ? b1 : (q == 2) ? b2 : b3;
      int base = (q == 0) ? ro0 : (q == 1) ? ro1 : (q == 2) ? ro2 : ro3;
      int off = base + __popcll(myb & ((1ULL << lane) - 1ULL));
      if (off < CAP) {
        float fx = pfx[c], fy = pfy[c];
        float gx = 1.0f - fx, gy = 1.0f - fy;
        edge_m[(size_t)row * CAP + off] = c * 64 + lane;
        edge_w[(size_t)row * CAP + off] =
            make_float4(gx * gy, gx * fy, fx * gy, fx * fy);
      }
    }
    ro0 += __popcll(b0); ro1 += __popcll(b1);
    ro2 += __popcll(b2); ro3 += __popcll(b3);
  }
  if (lane == 0) {
    int C0 = min(qt0, CAP), C1 = min(qt1, CAP);
    int C2 = min(qt2, CAP), C3c = min(qt3, CAP);
    cnt4[row] = make_int4(C0, C1 - C0, C2 - C1, C3c - C2);
    deginv[row] = 1.0f / (float)(qt3 > 0 ? qt3 : 1);
  }
}

// ---------------- gather: s[row, k*CIN + c] = deginv * sum basis_k * h[m,c] ----------------
// 256 threads = 4 waves, ONE ROW PER WAVE; grid 4096, XCD-swizzled so batch b's
// blocks share an XCD (h slice <=512KB L2-resident). Wave stages its row's edge
// list (m + precomputed weights) to LDS, then hot loop: 2 broadcast LDS reads
// + contiguous 128/256B global h gather (L2 hit) + 2 cvt + 4*CH FMAs, unroll 4.
// __launch_bounds__(256,8) pins VGPR <= 64 (8 waves/SIMD; lean body fits).
// Quadrant runs give static accumulator targets. CH = CIN/64 channels/lane.
template<int CH>
__global__ __launch_bounds__(256, 8) void gather_kernel(
    const _Float16* __restrict__ hsrc,   // [16384][CIN] fp16
    const int* __restrict__ edge_m, const float4* __restrict__ edge_w,
    const int4* __restrict__ cnt4,
    const float* __restrict__ deginv,
    _Float16* __restrict__ sp) {         // [16384][KP]
  const int CIN = 64 * CH, KP = 10 * CIN;
  __shared__ float4 eshw[4][CAP];
  __shared__ int eshm[4][CAP];
  int wave = threadIdx.x >> 6, lane = threadIdx.x & 63;
  int xcd = blockIdx.x & 7;
  int j = blockIdx.x >> 3;
  int b = xcd * 4 + (j >> 7);
  int n = ((j & 127) << 2) + wave;          // row within batch
  int row = (b << 9) + n;
  int4 c4 = cnt4[row];
  int e1 = c4.x, e2 = e1 + c4.y, e3 = e2 + c4.z, e4 = e3 + c4.w;
  size_t ebase = (size_t)row * CAP;
  for (int i = lane; i < e4; i += 64) {     // wave-private region, no barrier
    eshw[wave][i] = edge_w[ebase + i];
    eshm[wave][i] = edge_m[ebase + i];
  }
  float di = deginv[row];
  const _Float16* hb = hsrc + (size_t)b * N_ * CIN + lane * CH;

  float acc[3][3][CH];
  #pragma unroll
  for (int kx = 0; kx < 3; ++kx)
    #pragma unroll
    for (int ky = 0; ky < 3; ++ky)
      #pragma unroll
      for (int c = 0; c < CH; ++c) acc[kx][ky][c] = 0.0f;

#define EDGE_BODY(E, KX, KY) {                                        \
    int m = eshm[wave][E];                                            \
    float4 wv = eshw[wave][E];                                        \
    float hv[CH];                                                     \
    if (CH == 1) {                                                    \
      hv[0] = (float)hb[(size_t)m * 64];                              \
    } else {                                                          \
      unsigned u = *(const unsigned*)&hb[(size_t)m * 128];            \
      f16x2 hp = __builtin_bit_cast(f16x2, u);                        \
      hv[0] = (float)hp[0]; hv[CH - 1] = (float)hp[1];                \
    }                                                                 \
    _Pragma("unroll")                                                 \
    for (int c = 0; c < CH; ++c) {                                    \
      acc[KX][KY][c]         += wv.x * hv[c];                         \
      acc[KX][KY + 1][c]     += wv.y * hv[c];                         \
      acc[KX + 1][KY][c]     += wv.z * hv[c];                         \
      acc[KX + 1][KY + 1][c] += wv.w * hv[c];                         \
    } }

  #pragma unroll 4
  for (int e = 0; e < e1; ++e) EDGE_BODY(e, 0, 0)    // quad0: kx0=0, ky0=0
  #pragma unroll 4
  for (int e = e1; e < e2; ++e) EDGE_BODY(e, 1, 0)   // quad1: kx0=1, ky0=0
  #pragma unroll 4
  for (int e = e2; e < e3; ++e) EDGE_BODY(e, 0, 1)   // quad2: kx0=0, ky0=1
  #pragma unroll 4
  for (int e = e3; e < e4; ++e) EDGE_BODY(e, 1, 1)   // quad3: kx0=1, ky0=1
#undef EDGE_BODY

  // store: k = kx*3 + ky (reference reshape order); cols k*CIN + lane*CH
  _Float16* sr = sp + (size_t)row * KP + lane * CH;
  #pragma unroll
  for (int kx = 0; kx < 3; ++kx)
    #pragma unroll
    for (int ky = 0; ky < 3; ++ky) {
      int k = kx * 3 + ky;
      if (CH == 1) {
        sr[(size_t)k * CIN] = (_Float16)(acc[kx][ky][0] * di);
      } else {
        f16x2 p;
        p[0] = (_Float16)(acc[kx][ky][0] * di);
        p[1] = (_Float16)(acc[kx][ky][CH - 1] * di);
        *(f16x2*)&sr[(size_t)k * CIN] = p;
      }
    }
  // root column: h passthrough
  if (CH == 1) {
    sr[(size_t)9 * CIN] = hb[(size_t)n * 64];
  } else {
    *(unsigned*)&sr[(size_t)9 * CIN] = *(const unsigned*)&hb[(size_t)n * 128];
  }
}

// ---------------- dense GEMM: out[m,f] = relu( A[m,:]@Wt[f,:] + bias[f] ) ----------------
// A fp16 [16384][KP], Wt fp16 [64][KP]. M-tile 16 (grid 1024 = 4 blocks/CU),
// 256 thr = 4 waves; wave owns one 16x16 output tile (1 MFMA/K-chunk).
// Double-buffered LDS (23KB) with issue-early/write-late staging (T14);
// A staged by threads 0-127 (1 float4/step), W by all (2 float4/step).
// Epilogue: fp16 h-out and/or fused max-pool (atomicMax on uint bits, relu>=0).
#define GBK  64
#define GLDK 72
__global__ __launch_bounds__(256) void gemm_s_kernel(
    const _Float16* __restrict__ A, const _Float16* __restrict__ Wt,
    const float* __restrict__ bias, _Float16* __restrict__ hout,
    unsigned int* __restrict__ gmax, int KP) {
  __shared__ __attribute__((aligned(16))) _Float16 As[2][16 * GLDK];
  __shared__ __attribute__((aligned(16))) _Float16 Ws[2][64 * GLDK];
  int bm = blockIdx.x << 4;
  int tid = threadIdx.x, wave = tid >> 6, lane = tid & 63;
  int lr = lane & 15, quad = lane >> 4;
  int srow = tid >> 3, sck = (tid & 7) * 8;   // A: rows 0-15 (tid<128); W: rows srow, srow+32
  const size_t aoff = (size_t)(bm + srow) * KP + sck;
  const size_t woff = (size_t)srow * KP + sck;

  f32x4 acc = {0.f, 0.f, 0.f, 0.f};
  // stage step 0 directly
  {
    if (tid < 128) *(float4*)&As[0][srow * GLDK + sck] = *(const float4*)&A[aoff];
    *(float4*)&Ws[0][srow * GLDK + sck]        = *(const float4*)&Wt[woff];
    *(float4*)&Ws[0][(srow + 32) * GLDK + sck] = *(const float4*)&Wt[woff + (size_t)32 * KP];
  }
  int S = KP / GBK, cur = 0;
  float4 pa0, pw0, pw1;
  for (int s = 0; s < S; ++s) {
    if (s + 1 < S) {                 // issue next tile's loads (no wait)
      int k0 = (s + 1) * GBK;
      if (tid < 128) pa0 = *(const float4*)&A[aoff + k0];
      pw0 = *(const float4*)&Wt[woff + k0];
      pw1 = *(const float4*)&Wt[woff + (size_t)32 * KP + k0];
    }
    __syncthreads();                 // buf[cur] ready for all waves
    #pragma unroll
    for (int kk = 0; kk < GBK; kk += 32) {
      f16x8 bf = *(const f16x8*)&Ws[cur][((wave << 4) + lr) * GLDK + kk + quad * 8];
      f16x8 af = *(const f16x8*)&As[cur][lr * GLDK + kk + quad * 8];
      acc = __builtin_amdgcn_mfma_f32_16x16x32_f16(af, bf, acc, 0, 0, 0);
    }
    if (s + 1 < S) {                 // write-late into the other buffer
      int nb = cur ^ 1;
      if (tid < 128) *(float4*)&As[nb][srow * GLDK + sck] = pa0;
      *(float4*)&Ws[nb][srow * GLDK + sck]        = pw0;
      *(float4*)&Ws[nb][(srow + 32) * GLDK + sck] = pw1;
    }
    cur ^= 1;
  }
  // epilogue: C layout col = lane&15 (here: W col f), row = quad*4 + r
  int b = bm >> 9;
  int f = (wave << 4) + lr;
  float bs = bias[f];
  float vmax = 0.0f;
  #pragma unroll
  for (int r = 0; r < 4; ++r) {
    int m = bm + (quad << 2) + r;
    float v = fmaxf(acc[r] + bs, 0.0f);
    if (hout) hout[(size_t)m * F_ + f] = (_Float16)v;
    vmax = fmaxf(vmax, v);
  }
  if (gmax) atomicMax(&gmax[(b << 6) + f], __float_as_uint(vmax));
}

// ---------------- FC from pooled features ----------------
__global__ __launch_bounds__(64) void fc_kernel(
    const float* __restrict__ g, const float* __restrict__ fcw,
    const float* __restrict__ fcb, float* __restrict__ out) {
  int b = blockIdx.x;
  int f = threadIdx.x;
  __shared__ float gs[64];
  gs[f] = g[b * F_ + f];
  __syncthreads();
  if (f < 10) {
    float s = fcb[f];
    #pragma unroll
    for (int c = 0; c < 64; ++c) s += gs[c] * fcw[c * 10 + f];
    out[b * 10 + f] = s;
  }
}

extern "C" void kernel_launch(void* const* d_in, const int* in_sizes, int n_in,
                              void* d_out, int out_size, void* d_ws, size_t ws_size,
                              hipStream_t stream) {
  const float* x     = (const float*)d_in[0];
  const float* coord = (const float*)d_in[1];
  const float* adj   = (const float*)d_in[2];
  const float* w0    = (const float*)d_in[3];
  const float* root0 = (const float*)d_in[4];
  const float* b0    = (const float*)d_in[5];
  const float* w1    = (const float*)d_in[6];
  const float* root1 = (const float*)d_in[7];
  const float* b1    = (const float*)d_in[8];
  const float* w2    = (const float*)d_in[9];
  const float* root2 = (const float*)d_in[10];
  const float* b2    = (const float*)d_in[11];
  const float* fcw   = (const float*)d_in[12];
  const float* fcb   = (const float*)d_in[13];
  float* out = (float*)d_out;

  char* ws = (char*)d_ws;
  size_t off = 0;
  auto alloc = [&](size_t bytes) {
    void* p = ws + off;
    off = (off + bytes + 255) & ~(size_t)255;
    return p;
  };
  const int R = B_ * N_;  // 16384
  int*    edge_m  = (int*)   alloc((size_t)R * CAP * 4);
  float4* edge_w  = (float4*)alloc((size_t)R * CAP * 16);
  int4*   cnt4    = (int4*)  alloc((size_t)R * 16);
  float*  deginv  = (float*) alloc((size_t)R * 4);
  _Float16* hx    = (_Float16*)alloc((size_t)R * 128 * 2);   // fp16 x
  _Float16* wt0   = (_Float16*)alloc((size_t)64 * 1280 * 2);
  _Float16* wt1   = (_Float16*)alloc((size_t)64 * 640 * 2);
  _Float16* wt2   = (_Float16*)alloc((size_t)64 * 640 * 2);
  _Float16* sp    = (_Float16*)alloc((size_t)R * 1280 * 2);  // s (max K)
  _Float16* hA    = (_Float16*)alloc((size_t)R * 64 * 2);
  _Float16* hB    = (_Float16*)alloc((size_t)R * 64 * 2);
  unsigned int* gmax = (unsigned int*)alloc((size_t)B_ * F_ * 4);

  preprocess_kernel<<<R / 8, 512, 0, stream>>>(
      adj, coord, edge_m, edge_w, cnt4, deginv, gmax,
      x, hx, w0, root0, w1, root1, w2, root2, wt0, wt1, wt2);

  // layer 0: CIN=128, K = 1280
  gather_kernel<2><<<R / 4, 256, 0, stream>>>(hx, edge_m, edge_w, cnt4, deginv, sp);
  gemm_s_kernel<<<R / 16, 256, 0, stream>>>(sp, wt0, b0, hA, nullptr, 1280);

  // layer 1: CIN=64, K = 640
  gather_kernel<1><<<R / 4, 256, 0, stream>>>(hA, edge_m, edge_w, cnt4, deginv, sp);
  gemm_s_kernel<<<R / 16, 256, 0, stream>>>(sp, wt1, b1, hB, nullptr, 640);

  // layer 2: CIN=64, K = 640 — fused max-pool
  gather_kernel<1><<<R / 4, 256, 0, stream>>>(hB, edge_m, edge_w, cnt4, deginv, sp);
  gemm_s_kernel<<<R / 16, 256, 0, stream>>>(sp, wt2, b2, nullptr, gmax, 640);

  fc_kernel<<<B_, 64, 0, stream>>>((const float*)gmax, fcw, fcb, out);
}

// Round 22
// 202.225 us; speedup vs baseline: 1.0648x; 1.0648x over previous
//
#include <hip/hip_runtime.h>

// SplineCNN on MI355X — aggregate-before-GEMM, L2-direct gather (FINAL, R20).
//
// Math order: s[n, k*CIN+c] = deginv * sum_{m in N(n)} basis_k(n,m) * h[m,c],
// root column appended -> one dense GEMM per layer:
//   out = relu( [s | h] @ [w; root] + bias ),  K = 10*CIN, N = 64.
// Measured best 206.3us (R20; baseline was 277.6). Design ledger:
//  - gather: lean body, VGPR<=64 via launch_bounds(256,8) -> 8 waves/SIMD
//    (R13); precomputed tap weights in edge_w (R14). Deeper pipelines/unrolls
//    spill or halve occupancy (R8/R11/R18); slot-parallel (R12), fusion
//    (R7/R17), quadrant-per-wave (R10) all falsified with counter evidence.
//  - preprocess: barrier-free wave-per-row, two ballot passes, no LDS (R16);
//    merged with x->fp16 convert + weight pack + gmax zero.
//  - GEMM: M-tile 32, grid 512 = 2 blocks/CU (R20 optimum: 64 = too little
//    TLP for load-stall overlap; 16 = W-staging overhead dominates, R21).
//  - XCD swizzle on gather: batch b's blocks on XCD b>>2 (h L2-resident).
// All tensors fp16 (fp32 accumulate in gather + MFMA); layer-2 GEMM epilogue
// fuses global max-pool via uint-bitcast atomicMax (relu >= 0).

#define B_   32
#define N_   512
#define F_   64
#define CAP  128          // max neighbors per node (mean ~31; P(>128) ~ 18 sigma)

typedef float f32x4 __attribute__((ext_vector_type(4)));
typedef _Float16 f16x8 __attribute__((ext_vector_type(8)));
typedef _Float16 f16x2 __attribute__((ext_vector_type(2)));

// ---------------- preprocess: wave-per-row, barrier-free ----------------
// edge_m[row*CAP+i] = neighbor index m; edge_w[row*CAP+i] = {w00,w01,w10,w11}
// (bilinear tap weights, f32, precomputed). Sorted by quad = kx0 + 2*ky0,
// ascending m within each quad. cnt4[row] = clamped cumulative quad counts;
// deginv = 1/clip(deg,1). Grid 2048 x 512: wave w of block i handles row
// i*8+w. Also merged prep (x fp32->fp16 + pack [w;root] -> Wt) + gmax zero.
__global__ __launch_bounds__(512, 8) void preprocess_kernel(
    const float* __restrict__ adj, const float* __restrict__ coord,
    int* __restrict__ edge_m, float4* __restrict__ edge_w,
    int4* __restrict__ cnt4,
    float* __restrict__ deginv, unsigned int* __restrict__ gmax,
    const float* __restrict__ x, _Float16* __restrict__ hx,
    const float* __restrict__ w0, const float* __restrict__ root0,
    const float* __restrict__ w1, const float* __restrict__ root1,
    const float* __restrict__ w2, const float* __restrict__ root2,
    _Float16* __restrict__ wt0, _Float16* __restrict__ wt1,
    _Float16* __restrict__ wt2) {
  int tid = threadIdx.x, wave = tid >> 6, lane = tid & 63;
  if (tid == 0) gmax[blockIdx.x] = 0u;   // grid 2048 == B_*F_

  // ---- merged prep: idx space [0, R*32) convx; then packw for 3 layers ----
  {
    int idx = blockIdx.x * 512 + tid;    // covers 1,048,576 >= 688,128
    const int CX = B_ * N_ * 32;
    const int S0 = 64 * 1280, S1 = 64 * 640;
    if (idx < CX) {
      float4 v = ((const float4*)x)[idx];
      f16x2 p0, p1;
      p0[0] = (_Float16)v.x; p0[1] = (_Float16)v.y;
      p1[0] = (_Float16)v.z; p1[1] = (_Float16)v.w;
      uint2 u;
      u.x = __builtin_bit_cast(unsigned, p0);
      u.y = __builtin_bit_cast(unsigned, p1);
      ((uint2*)hx)[idx] = u;
    } else if (idx < CX + S0 + 2 * S1) {
      int r = idx - CX;
      const float *w, *root; _Float16* wt; int KP, CIN;
      if (r < S0)           { w = w0; root = root0; wt = wt0; KP = 1280; CIN = 128; }
      else if (r < S0 + S1) { w = w1; root = root1; wt = wt1; KP = 640;  CIN = 64;  r -= S0; }
      else                  { w = w2; root = root2; wt = wt2; KP = 640;  CIN = 64;  r -= S0 + S1; }
      int f = r / KP, k = r - f * KP;
      int ks = k / CIN, c = k - ks * CIN;
      float v = (ks < 9) ? w[((size_t)ks * CIN + c) * F_ + f]
                         : root[(size_t)c * F_ + f];
      wt[(size_t)f * KP + k] = (_Float16)v;
    }
  }

  int row = blockIdx.x * 8 + wave;       // one row per wave
  int b = row >> 9;
  float cxn = coord[(size_t)row * 2 + 0];
  float cyn = coord[(size_t)row * 2 + 1];

  // ---- pass 1: load + classify 8 chunks of 64; wave-uniform quad totals ----
  int   pq[8];                  // quad (0..3) or -1 if no edge
  float pfx[8], pfy[8];
  int q0 = 0, q1 = 0, q2 = 0, q3 = 0;
  #pragma unroll
  for (int c = 0; c < 8; ++c) {
    int m = c * 64 + lane;
    float a = adj[(size_t)row * N_ + m];
    bool flag = (a != 0.0f);
    float cxm = coord[(size_t)(b * N_ + m) * 2 + 0];
    float cym = coord[(size_t)(b * N_ + m) * 2 + 1];
    float vx = cxm - cxn + 1.0f;         // = u*2 (K-1 = 2, u in [0,1])
    float vy = cym - cyn + 1.0f;
    float i0x = fminf(fmaxf(floorf(vx), 0.0f), 1.0f);
    float i0y = fminf(fmaxf(floorf(vy), 0.0f), 1.0f);
    pfx[c] = vx - i0x;
    pfy[c] = vy - i0y;
    int quad = (int)i0x + 2 * (int)i0y;  // 0..3
    pq[c] = flag ? quad : -1;
    q0 += __popcll(__ballot(flag && quad == 0));
    q1 += __popcll(__ballot(flag && quad == 1));
    q2 += __popcll(__ballot(flag && quad == 2));
    q3 += __popcll(__ballot(flag && quad == 3));
  }
  int qt0 = q0, qt1 = q0 + q1, qt2 = qt1 + q2, qt3 = qt2 + q3;

  // ---- pass 2: running per-quad offsets -> quad-sorted edge writes ----
  int ro0 = 0, ro1 = qt0, ro2 = qt1, ro3 = qt2;   // quad base offsets
  #pragma unroll
  for (int c = 0; c < 8; ++c) {
    unsigned long long b0 = __ballot(pq[c] == 0);
    unsigned long long b1 = __ballot(pq[c] == 1);
    unsigned long long b2 = __ballot(pq[c] == 2);
    unsigned long long b3 = __ballot(pq[c] == 3);
    int q = pq[c];
    if (q >= 0) {
      unsigned long long myb = (q == 0) ? b0 : (q == 1) ? b1 : (q == 2) ? b2 : b3;
      int base = (q == 0) ? ro0 : (q == 1) ? ro1 : (q == 2) ? ro2 : ro3;
      int off = base + __popcll(myb & ((1ULL << lane) - 1ULL));
      if (off < CAP) {
        float fx = pfx[c], fy = pfy[c];
        float gx = 1.0f - fx, gy = 1.0f - fy;
        edge_m[(size_t)row * CAP + off] = c * 64 + lane;
        edge_w[(size_t)row * CAP + off] =
            make_float4(gx * gy, gx * fy, fx * gy, fx * fy);
      }
    }
    ro0 += __popcll(b0); ro1 += __popcll(b1);
    ro2 += __popcll(b2); ro3 += __popcll(b3);
  }
  if (lane == 0) {
    int C0 = min(qt0, CAP), C1 = min(qt1, CAP);
    int C2 = min(qt2, CAP), C3c = min(qt3, CAP);
    cnt4[row] = make_int4(C0, C1 - C0, C2 - C1, C3c - C2);
    deginv[row] = 1.0f / (float)(qt3 > 0 ? qt3 : 1);
  }
}

// ---------------- gather: s[row, k*CIN + c] = deginv * sum basis_k * h[m,c] ----------------
// 256 threads = 4 waves, ONE ROW PER WAVE; grid 4096, XCD-swizzled so batch b's
// blocks share an XCD (h slice <=512KB L2-resident). Wave stages its row's edge
// list (m + precomputed weights) to LDS, then hot loop: 2 broadcast LDS reads
// + contiguous 128/256B global h gather (L2 hit) + 2 cvt + 4*CH FMAs, unroll 4.
// __launch_bounds__(256,8) pins VGPR <= 64 (8 waves/SIMD; lean body fits).
// Quadrant runs give static accumulator targets. CH = CIN/64 channels/lane.
template<int CH>
__global__ __launch_bounds__(256, 8) void gather_kernel(
    const _Float16* __restrict__ hsrc,   // [16384][CIN] fp16
    const int* __restrict__ edge_m, const float4* __restrict__ edge_w,
    const int4* __restrict__ cnt4,
    const float* __restrict__ deginv,
    _Float16* __restrict__ sp) {         // [16384][KP]
  const int CIN = 64 * CH, KP = 10 * CIN;
  __shared__ float4 eshw[4][CAP];
  __shared__ int eshm[4][CAP];
  int wave = threadIdx.x >> 6, lane = threadIdx.x & 63;
  int xcd = blockIdx.x & 7;
  int j = blockIdx.x >> 3;
  int b = xcd * 4 + (j >> 7);
  int n = ((j & 127) << 2) + wave;          // row within batch
  int row = (b << 9) + n;
  int4 c4 = cnt4[row];
  int e1 = c4.x, e2 = e1 + c4.y, e3 = e2 + c4.z, e4 = e3 + c4.w;
  size_t ebase = (size_t)row * CAP;
  for (int i = lane; i < e4; i += 64) {     // wave-private region, no barrier
    eshw[wave][i] = edge_w[ebase + i];
    eshm[wave][i] = edge_m[ebase + i];
  }
  float di = deginv[row];
  const _Float16* hb = hsrc + (size_t)b * N_ * CIN + lane * CH;

  float acc[3][3][CH];
  #pragma unroll
  for (int kx = 0; kx < 3; ++kx)
    #pragma unroll
    for (int ky = 0; ky < 3; ++ky)
      #pragma unroll
      for (int c = 0; c < CH; ++c) acc[kx][ky][c] = 0.0f;

#define EDGE_BODY(E, KX, KY) {                                        \
    int m = eshm[wave][E];                                            \
    float4 wv = eshw[wave][E];                                        \
    float hv[CH];                                                     \
    if (CH == 1) {                                                    \
      hv[0] = (float)hb[(size_t)m * 64];                              \
    } else {                                                          \
      unsigned u = *(const unsigned*)&hb[(size_t)m * 128];            \
      f16x2 hp = __builtin_bit_cast(f16x2, u);                        \
      hv[0] = (float)hp[0]; hv[CH - 1] = (float)hp[1];                \
    }                                                                 \
    _Pragma("unroll")                                                 \
    for (int c = 0; c < CH; ++c) {                                    \
      acc[KX][KY][c]         += wv.x * hv[c];                         \
      acc[KX][KY + 1][c]     += wv.y * hv[c];                         \
      acc[KX + 1][KY][c]     += wv.z * hv[c];                         \
      acc[KX + 1][KY + 1][c] += wv.w * hv[c];                         \
    } }

  #pragma unroll 4
  for (int e = 0; e < e1; ++e) EDGE_BODY(e, 0, 0)    // quad0: kx0=0, ky0=0
  #pragma unroll 4
  for (int e = e1; e < e2; ++e) EDGE_BODY(e, 1, 0)   // quad1: kx0=1, ky0=0
  #pragma unroll 4
  for (int e = e2; e < e3; ++e) EDGE_BODY(e, 0, 1)   // quad2: kx0=0, ky0=1
  #pragma unroll 4
  for (int e = e3; e < e4; ++e) EDGE_BODY(e, 1, 1)   // quad3: kx0=1, ky0=1
#undef EDGE_BODY

  // store: k = kx*3 + ky (reference reshape order); cols k*CIN + lane*CH
  _Float16* sr = sp + (size_t)row * KP + lane * CH;
  #pragma unroll
  for (int kx = 0; kx < 3; ++kx)
    #pragma unroll
    for (int ky = 0; ky < 3; ++ky) {
      int k = kx * 3 + ky;
      if (CH == 1) {
        sr[(size_t)k * CIN] = (_Float16)(acc[kx][ky][0] * di);
      } else {
        f16x2 p;
        p[0] = (_Float16)(acc[kx][ky][0] * di);
        p[1] = (_Float16)(acc[kx][ky][CH - 1] * di);
        *(f16x2*)&sr[(size_t)k * CIN] = p;
      }
    }
  // root column: h passthrough
  if (CH == 1) {
    sr[(size_t)9 * CIN] = hb[(size_t)n * 64];
  } else {
    *(unsigned*)&sr[(size_t)9 * CIN] = *(const unsigned*)&hb[(size_t)n * 128];
  }
}

// ---------------- dense GEMM: out[m,f] = relu( A[m,:]@Wt[f,:] + bias[f] ) ----------------
// A fp16 [16384][KP], Wt fp16 [64][KP]. M-tile 32 (grid 512 = 2 blocks/CU),
// 256 thr = 4 waves; wave owns a 16-COL slice of all 32 rows (2 MFMA/K-chunk).
// Double-buffered LDS (27.6KB) with issue-early/write-late staging (T14);
// 3 float4 staging loads/thread/step. Epilogue: fp16 h-out and/or fused
// max-pool (atomicMax on uint bits, relu >= 0).
#define GBK  64
#define GLDK 72
__global__ __launch_bounds__(256) void gemm_s_kernel(
    const _Float16* __restrict__ A, const _Float16* __restrict__ Wt,
    const float* __restrict__ bias, _Float16* __restrict__ hout,
    unsigned int* __restrict__ gmax, int KP) {
  __shared__ __attribute__((aligned(16))) _Float16 As[2][32 * GLDK];
  __shared__ __attribute__((aligned(16))) _Float16 Ws[2][64 * GLDK];
  int bm = blockIdx.x << 5;
  int tid = threadIdx.x, wave = tid >> 6, lane = tid & 63;
  int lr = lane & 15, quad = lane >> 4;
  int srow = tid >> 3, sck = (tid & 7) * 8;   // A: row srow; W: rows srow, srow+32
  const size_t aoff = (size_t)(bm + srow) * KP + sck;
  const size_t woff = (size_t)srow * KP + sck;

  f32x4 acc0 = {0.f, 0.f, 0.f, 0.f}, acc1 = {0.f, 0.f, 0.f, 0.f};
  // stage step 0 directly
  {
    *(float4*)&As[0][srow * GLDK + sck]        = *(const float4*)&A[aoff];
    *(float4*)&Ws[0][srow * GLDK + sck]        = *(const float4*)&Wt[woff];
    *(float4*)&Ws[0][(srow + 32) * GLDK + sck] = *(const float4*)&Wt[woff + (size_t)32 * KP];
  }
  int S = KP / GBK, cur = 0;
  float4 pa0, pw0, pw1;
  for (int s = 0; s < S; ++s) {
    if (s + 1 < S) {                 // issue next tile's loads (no wait)
      int k0 = (s + 1) * GBK;
      pa0 = *(const float4*)&A[aoff + k0];
      pw0 = *(const float4*)&Wt[woff + k0];
      pw1 = *(const float4*)&Wt[woff + (size_t)32 * KP + k0];
    }
    __syncthreads();                 // buf[cur] ready for all waves
    #pragma unroll
    for (int kk = 0; kk < GBK; kk += 32) {
      f16x8 bf  = *(const f16x8*)&Ws[cur][((wave << 4) + lr) * GLDK + kk + quad * 8];
      f16x8 af0 = *(const f16x8*)&As[cur][lr * GLDK + kk + quad * 8];
      f16x8 af1 = *(const f16x8*)&As[cur][(16 + lr) * GLDK + kk + quad * 8];
      acc0 = __builtin_amdgcn_mfma_f32_16x16x32_f16(af0, bf, acc0, 0, 0, 0);
      acc1 = __builtin_amdgcn_mfma_f32_16x16x32_f16(af1, bf, acc1, 0, 0, 0);
    }
    if (s + 1 < S) {                 // write-late into the other buffer
      int nb = cur ^ 1;
      *(float4*)&As[nb][srow * GLDK + sck]        = pa0;
      *(float4*)&Ws[nb][srow * GLDK + sck]        = pw0;
      *(float4*)&Ws[nb][(srow + 32) * GLDK + sck] = pw1;
    }
    cur ^= 1;
  }
  // epilogue: C layout col = lane&15 (here: W col f), row = quad*4 + r
  int b = bm >> 9;
  int f = (wave << 4) + lr;
  float bs = bias[f];
  float vmax = 0.0f;
  #pragma unroll
  for (int r = 0; r < 4; ++r) {
    int m0 = bm + (quad << 2) + r;          // rows 0-15 tile
    float v0 = fmaxf(acc0[r] + bs, 0.0f);
    if (hout) hout[(size_t)m0 * F_ + f] = (_Float16)v0;
    vmax = fmaxf(vmax, v0);
    int m1 = bm + 16 + (quad << 2) + r;     // rows 16-31 tile
    float v1 = fmaxf(acc1[r] + bs, 0.0f);
    if (hout) hout[(size_t)m1 * F_ + f] = (_Float16)v1;
    vmax = fmaxf(vmax, v1);
  }
  if (gmax) atomicMax(&gmax[(b << 6) + f], __float_as_uint(vmax));
}

// ---------------- FC from pooled features ----------------
__global__ __launch_bounds__(64) void fc_kernel(
    const float* __restrict__ g, const float* __restrict__ fcw,
    const float* __restrict__ fcb, float* __restrict__ out) {
  int b = blockIdx.x;
  int f = threadIdx.x;
  __shared__ float gs[64];
  gs[f] = g[b * F_ + f];
  __syncthreads();
  if (f < 10) {
    float s = fcb[f];
    #pragma unroll
    for (int c = 0; c < 64; ++c) s += gs[c] * fcw[c * 10 + f];
    out[b * 10 + f] = s;
  }
}

extern "C" void kernel_launch(void* const* d_in, const int* in_sizes, int n_in,
                              void* d_out, int out_size, void* d_ws, size_t ws_size,
                              hipStream_t stream) {
  const float* x     = (const float*)d_in[0];
  const float* coord = (const float*)d_in[1];
  const float* adj   = (const float*)d_in[2];
  const float* w0    = (const float*)d_in[3];
  const float* root0 = (const float*)d_in[4];
  const float* b0    = (const float*)d_in[5];
  const float* w1    = (const float*)d_in[6];
  const float* root1 = (const float*)d_in[7];
  const float* b1    = (const float*)d_in[8];
  const float* w2    = (const float*)d_in[9];
  const float* root2 = (const float*)d_in[10];
  const float* b2    = (const float*)d_in[11];
  const float* fcw   = (const float*)d_in[12];
  const float* fcb   = (const float*)d_in[13];
  float* out = (float*)d_out;

  char* ws = (char*)d_ws;
  size_t off = 0;
  auto alloc = [&](size_t bytes) {
    void* p = ws + off;
    off = (off + bytes + 255) & ~(size_t)255;
    return p;
  };
  const int R = B_ * N_;  // 16384
  int*    edge_m  = (int*)   alloc((size_t)R * CAP * 4);
  float4* edge_w  = (float4*)alloc((size_t)R * CAP * 16);
  int4*   cnt4    = (int4*)  alloc((size_t)R * 16);
  float*  deginv  = (float*) alloc((size_t)R * 4);
  _Float16* hx    = (_Float16*)alloc((size_t)R * 128 * 2);   // fp16 x
  _Float16* wt0   = (_Float16*)alloc((size_t)64 * 1280 * 2);
  _Float16* wt1   = (_Float16*)alloc((size_t)64 * 640 * 2);
  _Float16* wt2   = (_Float16*)alloc((size_t)64 * 640 * 2);
  _Float16* sp    = (_Float16*)alloc((size_t)R * 1280 * 2);  // s (max K)
  _Float16* hA    = (_Float16*)alloc((size_t)R * 64 * 2);
  _Float16* hB    = (_Float16*)alloc((size_t)R * 64 * 2);
  unsigned int* gmax = (unsigned int*)alloc((size_t)B_ * F_ * 4);

  preprocess_kernel<<<R / 8, 512, 0, stream>>>(
      adj, coord, edge_m, edge_w, cnt4, deginv, gmax,
      x, hx, w0, root0, w1, root1, w2, root2, wt0, wt1, wt2);

  // layer 0: CIN=128, K = 1280
  gather_kernel<2><<<R / 4, 256, 0, stream>>>(hx, edge_m, edge_w, cnt4, deginv, sp);
  gemm_s_kernel<<<R / 32, 256, 0, stream>>>(sp, wt0, b0, hA, nullptr, 1280);

  // layer 1: CIN=64, K = 640
  gather_kernel<1><<<R / 4, 256, 0, stream>>>(hA, edge_m, edge_w, cnt4, deginv, sp);
  gemm_s_kernel<<<R / 32, 256, 0, stream>>>(sp, wt1, b1, hB, nullptr, 640);

  // layer 2: CIN=64, K = 640 — fused max-pool
  gather_kernel<1><<<R / 4, 256, 0, stream>>>(hB, edge_m, edge_w, cnt4, deginv, sp);
  gemm_s_kernel<<<R / 32, 256, 0, stream>>>(sp, wt2, b2, nullptr, gmax, 640);

  fc_kernel<<<B_, 64, 0, stream>>>((const float*)gmax, fcw, fcb, out);
}